// Round 8
// baseline (269.882 us; speedup 1.0000x reference)
//
#include <hip/hip_runtime.h>
#include <hip/hip_bf16.h>
#include <stdint.h>

#define NPAIRS 500000
#define NNODES 100000
#define DIM    128
#define D2     256
#define NBUCK  2048          // i>>6 -> 0..1562 used

typedef __bf16 bf16;
typedef __bf16 bf16x8 __attribute__((ext_vector_type(8)));
typedef __bf16 bf16x4 __attribute__((ext_vector_type(4)));
typedef float  f32x4  __attribute__((ext_vector_type(4)));

// =================== pack W1 -> per-lane A-operand fragments ===================
// W1'[k][n'] = n'<256 ? W1[k][n'] : W1[k+128][n'-256]
// w1p[((cg*4+kks)*64+lane)*8+j] = W1'[kks*32+(lane>>4)*8+j][cg*16+(lane&15)]
__global__ void pack_w1p(const float* __restrict__ W1, bf16* __restrict__ w1p) {
    int t = blockIdx.x * 256 + threadIdx.x;   // 0..8191
    int lane = t & 63;
    int kks = (t >> 6) & 3;
    int cg  = t >> 8;                          // 0..31
    int l15 = lane & 15, lg = lane >> 4;
    int np = cg * 16 + l15;                    // 0..511
    int k0 = kks * 32 + lg * 8;
    const float* src = (np < D2) ? (W1 + (long)k0 * D2 + np)
                                 : (W1 + (long)(k0 + 128) * D2 + (np - D2));
    bf16x8 v;
#pragma unroll
    for (int j = 0; j < 8; ++j) v[j] = (bf16)src[(long)j * D2];
    *(bf16x8*)((char*)w1p + ((long)t << 4)) = v;
}

// =================== phase 1: UV[node][512] = [x W1a | x W1b] ===================
// 64 nodes/block, 8 waves each owning 64 hc; LDS 16+64=80KB -> 2 blocks/CU.
__launch_bounds__(512, 2)
__global__ void gemm_uv(const float* __restrict__ x,
                        const bf16*  __restrict__ w1p,
                        bf16*        __restrict__ UV) {
    __shared__ char xt[64 * 256];    // 16 KB staged X (bf16, swizzled)
    __shared__ char hs[64 * 1024];   // 64 KB H-transpose buffer
    int tid  = threadIdx.x;
    int wave = tid >> 6, lane = tid & 63;
    int l15 = lane & 15, lg = lane >> 4;
    long nb = (long)blockIdx.x * 64;

    // stage 64 node rows fp32->bf16 (16 threads per 512B row, coalesced)
#pragma unroll
    for (int it = 0; it < 2; ++it) {
        int task = it * 512 + tid;          // 0..1023
        int r = task >> 4, c = task & 15;
        long node = nb + r;
        const float* src = x + (node < NNODES ? node : 0) * DIM + c * 8;
        float4 a = ((const float4*)src)[0];
        float4 b = ((const float4*)src)[1];
        bf16x8 v;
        v[0]=(bf16)a.x; v[1]=(bf16)a.y; v[2]=(bf16)a.z; v[3]=(bf16)a.w;
        v[4]=(bf16)b.x; v[5]=(bf16)b.y; v[6]=(bf16)b.z; v[7]=(bf16)b.w;
        *(bf16x8*)(xt + r * 256 + ((c * 16) ^ ((r & 15) << 4))) = v;
    }
    __syncthreads();

    f32x4 acc[4][4];
#pragma unroll
    for (int m = 0; m < 4; ++m)
#pragma unroll
        for (int nf = 0; nf < 4; ++nf)
            acc[m][nf] = (f32x4){0.f, 0.f, 0.f, 0.f};

#pragma unroll
    for (int kks = 0; kks < 4; ++kks) {
        bf16x8 xf[4];
        int kbyte = kks * 64 + lg * 16;
#pragma unroll
        for (int nf = 0; nf < 4; ++nf) {
            int r = nf * 16 + l15;
            xf[nf] = *(const bf16x8*)(xt + r * 256 + (kbyte ^ ((r & 15) << 4)));
        }
#pragma unroll
        for (int m = 0; m < 4; ++m) {
            int cg = wave * 4 + m;
            bf16x8 wf = *(const bf16x8*)((const char*)w1p +
                            (((cg * 4 + kks) * 64 + lane) << 4));
#pragma unroll
            for (int nf = 0; nf < 4; ++nf)
                acc[m][nf] = __builtin_amdgcn_mfma_f32_16x16x32_bf16(wf, xf[nf], acc[m][nf], 0, 0, 0);
        }
    }

    // dump acc -> hs: row=node(0..63), hc byte = wave*128 + m*32 + lg*8
#pragma unroll
    for (int m = 0; m < 4; ++m)
#pragma unroll
        for (int nf = 0; nf < 4; ++nf) {
            int row  = nf * 16 + l15;
            int col8 = wave * 128 + m * 32 + lg * 8;
            bf16x4 o;
            o[0] = (bf16)acc[m][nf][0];
            o[1] = (bf16)acc[m][nf][1];
            o[2] = (bf16)acc[m][nf][2];
            o[3] = (bf16)acc[m][nf][3];
            *(bf16x4*)(hs + row * 1024 + (col8 ^ ((row & 63) << 4))) = o;
        }
    __syncthreads();

    // coalesced store: each wave streams one full 1KB node row per iter
#pragma unroll
    for (int it = 0; it < 8; ++it) {
        int ci = it * 512 + tid;      // 0..4095
        int row = ci >> 6, c = ci & 63;
        bf16x8 v = *(const bf16x8*)(hs + row * 1024 + ((c * 16) ^ ((row & 63) << 4)));
        long node = nb + row;
        if (node < NNODES)
            *(bf16x8*)(UV + node * 512 + c * 8) = v;
    }
}

// =================== bucket sort by i (64-node buckets) ===================
__global__ void zero_cnt(int* __restrict__ cnt) {
    cnt[blockIdx.x * 1024 + threadIdx.x] = 0;
}

__global__ void hist_i(const int* __restrict__ junc, int* __restrict__ cnt) {
    int p = blockIdx.x * 512 + threadIdx.x;
    if (p < NPAIRS) atomicAdd(&cnt[junc[2 * p] >> 6], 1);
}

__global__ void scan2048(const int* __restrict__ cnt, int* __restrict__ off) {
    __shared__ int s[256];
    int t = threadIdx.x;
    int loc[8]; int sum = 0;
#pragma unroll
    for (int e = 0; e < 8; ++e) { loc[e] = sum; sum += cnt[t * 8 + e]; }
    s[t] = sum;
    __syncthreads();
    for (int d = 1; d < 256; d <<= 1) {
        int v = (t >= d) ? s[t - d] : 0;
        __syncthreads();
        s[t] += v;
        __syncthreads();
    }
    int pre = (t == 0) ? 0 : s[t - 1];
#pragma unroll
    for (int e = 0; e < 8; ++e) off[t * 8 + e] = pre + loc[e];
}

__global__ void scatter_pairs(const int* __restrict__ junc, int* __restrict__ off,
                              int4* __restrict__ sorted) {
    int p = blockIdx.x * 512 + threadIdx.x;
    if (p >= NPAIRS) return;
    int i = junc[2 * p], j = junc[2 * p + 1];
    int pos = atomicAdd(&off[i >> 6], 1);
    sorted[pos] = make_int4(i, j, p, 0);
}

// =================== phase 2 (sorted): blocked per-wave ranges ===================
__launch_bounds__(512)
__global__ void pair_pred_sorted(const bf16* __restrict__ UV,
                                 const int4* __restrict__ sorted,
                                 const float* __restrict__ b1,
                                 const float* __restrict__ w2,
                                 const float* __restrict__ b2,
                                 float* __restrict__ out) {
    int tid = threadIdx.x;
    int lane = tid & 63, half = lane >> 5, l31 = lane & 31;
    long w = (long)blockIdx.x * 8 + (tid >> 6);    // 0..8191
    const long RPW = (NPAIRS + 8191) / 8192;       // 62
    long start = w * RPW;
    long end = start + RPW; if (end > NPAIRS) end = NPAIRS;
    float b1c[8], w2c[8];
#pragma unroll
    for (int e = 0; e < 8; ++e) {
        int col = l31 * 8 + e;
        b1c[e] = b1[col];
        w2c[e] = w2[col];
    }
    float b2v = b2[0];
    for (long k = start + half; k < end; k += 2) {
        int4 rec = sorted[k];
        bf16x8 u = *(const bf16x8*)(UV + (long)rec.x * 512 + l31 * 8);
        bf16x8 v = *(const bf16x8*)(UV + (long)rec.y * 512 + 256 + l31 * 8);
        float s = 0.f;
#pragma unroll
        for (int e = 0; e < 8; ++e) {
            float h = (float)u[e] + (float)v[e] + b1c[e];
            s = fmaf(fmaxf(h, 0.f), w2c[e], s);
        }
        s += __shfl_xor(s, 1);
        s += __shfl_xor(s, 2);
        s += __shfl_xor(s, 4);
        s += __shfl_xor(s, 8);
        s += __shfl_xor(s, 16);
        if (l31 == 0) out[rec.z] = s + b2v;
    }
}

// =================== tier-2 phase 2 (unsorted, round-7) ===================
__launch_bounds__(512)
__global__ void pair_pred(const bf16* __restrict__ UV, const int* __restrict__ junc,
                          const float* __restrict__ b1, const float* __restrict__ w2,
                          const float* __restrict__ b2, float* __restrict__ out) {
    int tid = threadIdx.x;
    int lane = tid & 63, half = lane >> 5, l31 = lane & 31;
    long gw = (long)blockIdx.x * 8 + (tid >> 6);
    float b1c[8], w2c[8];
#pragma unroll
    for (int e = 0; e < 8; ++e) {
        int col = l31 * 8 + e;
        b1c[e] = b1[col];
        w2c[e] = w2[col];
    }
    float b2v = b2[0];
    const long HALF = NPAIRS / 2;
    for (long q = gw; q < HALF; q += 8192) {
        long p = 2 * q + half;
        int2 ij = ((const int2*)junc)[p];
        bf16x8 u = *(const bf16x8*)(UV + (long)ij.x * 512 + l31 * 8);
        bf16x8 v = *(const bf16x8*)(UV + (long)ij.y * 512 + 256 + l31 * 8);
        float s = 0.f;
#pragma unroll
        for (int e = 0; e < 8; ++e) {
            float h = (float)u[e] + (float)v[e] + b1c[e];
            s = fmaf(fmaxf(h, 0.f), w2c[e], s);
        }
        s += __shfl_xor(s, 1);
        s += __shfl_xor(s, 2);
        s += __shfl_xor(s, 4);
        s += __shfl_xor(s, 8);
        s += __shfl_xor(s, 16);
        if (l31 == 0) out[p] = s + b2v;
    }
}

// =================== tier-3 fallback: fused, known-correct ===================
__global__ void pack_w1(const float* __restrict__ W1, bf16* __restrict__ w1f) {
    int t = blockIdx.x * 256 + threadIdx.x;
    int lane = t & 63;
    int kk = (t >> 6) & 7;
    int cg = t >> 9;
    int l15 = lane & 15, lg = lane >> 4;
    bf16x8 v;
#pragma unroll
    for (int j = 0; j < 8; ++j)
        v[j] = (bf16)W1[(long)(kk * 32 + lg * 8 + j) * D2 + cg * 16 + l15];
    *(bf16x8*)((char*)w1f + ((long)t << 4)) = v;
}

__launch_bounds__(512, 2)
__global__ void fused_fb(const float* __restrict__ x, const int* __restrict__ junc,
                         const bf16* __restrict__ w1f, const float* __restrict__ b1,
                         const float* __restrict__ w2p, const float* __restrict__ b2,
                         float* __restrict__ out) {
    __shared__ char  atile[128 * 512];
    __shared__ float outp[4][128];
    int tid  = threadIdx.x;
    int wave = tid >> 6, lane = tid & 63;
    int l15 = lane & 15, lg = lane >> 4;
    int wr = wave >> 2, wc = wave & 3;
    long base_p = (long)blockIdx.x * 128;

    float bb[4][4], ww[4][4];
#pragma unroll
    for (int m = 0; m < 4; ++m)
#pragma unroll
        for (int r = 0; r < 4; ++r) {
            int hc = wc * 64 + m * 16 + lg * 4 + r;
            bb[m][r] = b1[hc];
            ww[m][r] = w2p[hc];
        }
#pragma unroll
    for (int it = 0; it < 8; ++it) {
        int task  = it * 512 + tid;
        int nr = task >> 4, chunk = task & 15;
        int r = nr >> 1, side = nr & 1;
        long p = base_p + r;
        int idx = (p < NPAIRS) ? junc[p * 2 + side] : 0;
        const float4* src = (const float4*)(x + (long)idx * DIM + chunk * 8);
        float4 a = src[0], b = src[1];
        bf16x8 v;
        v[0]=(bf16)a.x; v[1]=(bf16)a.y; v[2]=(bf16)a.z; v[3]=(bf16)a.w;
        v[4]=(bf16)b.x; v[5]=(bf16)b.y; v[6]=(bf16)b.z; v[7]=(bf16)b.w;
        int bir = side * 256 + chunk * 16;
        *(bf16x8*)(atile + r * 512 + (bir ^ ((r & 31) << 4))) = v;
    }
    __syncthreads();

    f32x4 acc[4][4];
#pragma unroll
    for (int m = 0; m < 4; ++m)
#pragma unroll
        for (int n = 0; n < 4; ++n)
            acc[m][n] = (f32x4){0.f, 0.f, 0.f, 0.f};
#pragma unroll
    for (int kk = 0; kk < 8; ++kk) {
        bf16x8 xf[4];
        int kbyte = kk * 64 + lg * 16;
#pragma unroll
        for (int n = 0; n < 4; ++n) {
            int r = wr * 64 + n * 16 + l15;
            xf[n] = *(const bf16x8*)(atile + r * 512 + (kbyte ^ ((r & 31) << 4)));
        }
#pragma unroll
        for (int m = 0; m < 4; ++m) {
            bf16x8 wf = *(const bf16x8*)((const char*)w1f +
                            ((((wc * 4 + m) * 8 + kk) * 64 + lane) << 4));
#pragma unroll
            for (int n = 0; n < 4; ++n)
                acc[m][n] = __builtin_amdgcn_mfma_f32_16x16x32_bf16(wf, xf[n], acc[m][n], 0, 0, 0);
        }
    }
#pragma unroll
    for (int n = 0; n < 4; ++n) {
        float s = 0.f;
#pragma unroll
        for (int m = 0; m < 4; ++m)
#pragma unroll
            for (int r = 0; r < 4; ++r)
                s = fmaf(fmaxf(acc[m][n][r] + bb[m][r], 0.f), ww[m][r], s);
        s += __shfl_xor(s, 16);
        s += __shfl_xor(s, 32);
        if (lg == 0) outp[wc][wr * 64 + n * 16 + l15] = s;
    }
    __syncthreads();
    if (tid < 128) {
        long p = base_p + tid;
        if (p < NPAIRS)
            out[p] = b2[0] + outp[0][tid] + outp[1][tid] + outp[2][tid] + outp[3][tid];
    }
}

extern "C" void kernel_launch(void* const* d_in, const int* in_sizes, int n_in,
                              void* d_out, int out_size, void* d_ws, size_t ws_size,
                              hipStream_t stream) {
    const float* x    = (const float*)d_in[0];
    const int*   junc = (const int*)  d_in[1];
    const float* W1   = (const float*)d_in[2];
    const float* b1   = (const float*)d_in[3];
    const float* W2   = (const float*)d_in[4];
    const float* b2   = (const float*)d_in[5];
    float* out = (float*)d_out;

    const size_t UV_B   = (size_t)NNODES * 512 * 2;        // 102,400,000
    const size_t W1P_B  = 131072;
    const size_t SORT_B = (size_t)NPAIRS * 16;             // 8,000,000
    const size_t CNT_B  = NBUCK * 4, OFF_B = NBUCK * 4;
    const size_t NEED_SORT  = UV_B + W1P_B + SORT_B + CNT_B + OFF_B;
    const size_t NEED_BASIC = UV_B + W1P_B;

    if (ws_size >= NEED_SORT) {
        bf16* UV     = (bf16*)d_ws;
        bf16* w1p    = (bf16*)((char*)d_ws + UV_B);
        int4* sorted = (int4*)((char*)d_ws + UV_B + W1P_B);
        int*  cnt    = (int*) ((char*)d_ws + UV_B + W1P_B + SORT_B);
        int*  off    = (int*) ((char*)d_ws + UV_B + W1P_B + SORT_B + CNT_B);

        hipLaunchKernelGGL(pack_w1p, dim3(32), dim3(256), 0, stream, W1, w1p);
        hipLaunchKernelGGL(zero_cnt, dim3(2), dim3(1024), 0, stream, cnt);
        hipLaunchKernelGGL(hist_i, dim3((NPAIRS + 511) / 512), dim3(512), 0, stream, junc, cnt);
        hipLaunchKernelGGL(scan2048, dim3(1), dim3(256), 0, stream, cnt, off);
        hipLaunchKernelGGL(scatter_pairs, dim3((NPAIRS + 511) / 512), dim3(512), 0, stream,
                           junc, off, sorted);
        hipLaunchKernelGGL(gemm_uv, dim3((NNODES + 63) / 64), dim3(512), 0, stream, x, w1p, UV);
        hipLaunchKernelGGL(pair_pred_sorted, dim3(1024), dim3(512), 0, stream,
                           UV, sorted, b1, W2, b2, out);
    } else if (ws_size >= NEED_BASIC) {
        bf16* UV  = (bf16*)d_ws;
        bf16* w1p = (bf16*)((char*)d_ws + UV_B);
        hipLaunchKernelGGL(pack_w1p, dim3(32), dim3(256), 0, stream, W1, w1p);
        hipLaunchKernelGGL(gemm_uv, dim3((NNODES + 63) / 64), dim3(512), 0, stream, x, w1p, UV);
        hipLaunchKernelGGL(pair_pred, dim3(1024), dim3(512), 0, stream,
                           UV, junc, b1, W2, b2, out);
    } else {
        bf16* w1f = (bf16*)d_ws;
        hipLaunchKernelGGL(pack_w1, dim3(32), dim3(256), 0, stream, W1, w1f);
        hipLaunchKernelGGL(fused_fb, dim3((NPAIRS + 127) / 128), dim3(512), 0, stream,
                           x, junc, w1f, b1, W2, b2, out);
    }
}

// Round 9
// 107.612 us; speedup vs baseline: 2.5079x; 2.5079x over previous
//
#include <hip/hip_runtime.h>
#include <hip/hip_bf16.h>
#include <stdint.h>

#define NPAIRS 500000
#define NNODES 100000
#define DIM    128
#define D2     256

typedef __bf16 bf16;
typedef __bf16 bf16x8 __attribute__((ext_vector_type(8)));
typedef __bf16 bf16x4 __attribute__((ext_vector_type(4)));
typedef float  f32x4  __attribute__((ext_vector_type(4)));

// =================== pack W1 -> per-lane A-operand fragments ===================
// W1'[k][n'] = n'<256 ? W1[k][n'] (U half, k 0..127) : W1[k+128][n'-256] (V half)
// w1p[((cg*4+kks)*64+lane)*8+j] = W1'[kks*32+(lane>>4)*8+j][cg*16+(lane&15)]
__global__ void pack_w1p(const float* __restrict__ W1, bf16* __restrict__ w1p) {
    int t = blockIdx.x * 256 + threadIdx.x;   // 0..8191
    int lane = t & 63;
    int kks = (t >> 6) & 3;
    int cg  = t >> 8;                          // 0..31
    int l15 = lane & 15, lg = lane >> 4;
    int np = cg * 16 + l15;                    // 0..511
    int k0 = kks * 32 + lg * 8;
    const float* src = (np < D2) ? (W1 + (long)k0 * D2 + np)
                                 : (W1 + (long)(k0 + 128) * D2 + (np - D2));
    bf16x8 v;
#pragma unroll
    for (int j = 0; j < 8; ++j) v[j] = (bf16)src[(long)j * D2];
    *(bf16x8*)((char*)w1p + ((long)t << 4)) = v;
}

// =================== phase 1: UV[node][512] = [x W1a | x W1b] ===================
// 64 nodes/block, 8 waves, 4 hc-passes of 128 hc (wave owns 16 hc/pass).
// acc = 16 VGPR -> target <=64 total regs -> 4 blocks/CU, 32 waves/CU.
__launch_bounds__(512, 8)
__global__ void gemm_uv(const float* __restrict__ x,
                        const bf16*  __restrict__ w1p,
                        bf16*        __restrict__ UV) {
    __shared__ char xt[64 * 256];    // 16 KB staged X (bf16, swizzled)
    __shared__ char hs[64 * 256];    // 16 KB H-transpose buffer (128 hc per pass)
    int tid  = threadIdx.x;
    int wave = tid >> 6, lane = tid & 63;
    int l15 = lane & 15, lg = lane >> 4;
    long nb = (long)blockIdx.x * 64;

    // stage 64 node rows fp32 -> bf16 (16 threads per 512B row, coalesced)
#pragma unroll
    for (int it = 0; it < 2; ++it) {
        int task = it * 512 + tid;          // 0..1023
        int r = task >> 4, c = task & 15;
        long node = nb + r;
        const float* src = x + (node < NNODES ? node : 0) * DIM + c * 8;
        float4 a = ((const float4*)src)[0];
        float4 b = ((const float4*)src)[1];
        bf16x8 v;
        v[0]=(bf16)a.x; v[1]=(bf16)a.y; v[2]=(bf16)a.z; v[3]=(bf16)a.w;
        v[4]=(bf16)b.x; v[5]=(bf16)b.y; v[6]=(bf16)b.z; v[7]=(bf16)b.w;
        *(bf16x8*)(xt + r * 256 + ((c * 16) ^ ((r & 15) << 4))) = v;
    }
    __syncthreads();

#pragma unroll 1
    for (int p = 0; p < 4; ++p) {
        f32x4 acc[4];
#pragma unroll
        for (int nf = 0; nf < 4; ++nf) acc[nf] = (f32x4){0.f, 0.f, 0.f, 0.f};

        int cg = p * 8 + wave;               // this wave's 16-hc column group
#pragma unroll
        for (int kks = 0; kks < 4; ++kks) {
            bf16x8 wf = *(const bf16x8*)((const char*)w1p +
                            (((cg * 4 + kks) * 64 + lane) << 4));
            int kbyte = kks * 64 + lg * 16;
#pragma unroll
            for (int nf = 0; nf < 4; ++nf) {
                int r = nf * 16 + l15;
                bf16x8 xf = *(const bf16x8*)(xt + r * 256 + (kbyte ^ ((r & 15) << 4)));
                acc[nf] = __builtin_amdgcn_mfma_f32_16x16x32_bf16(wf, xf, acc[nf], 0, 0, 0);
            }
        }

        // dump acc -> hs: row = local node, col8 = wave*32 + lg*8 (8B bf16x4)
#pragma unroll
        for (int nf = 0; nf < 4; ++nf) {
            int row  = nf * 16 + l15;
            int col8 = wave * 32 + lg * 8;
            bf16x4 o;
            o[0] = (bf16)acc[nf][0];
            o[1] = (bf16)acc[nf][1];
            o[2] = (bf16)acc[nf][2];
            o[3] = (bf16)acc[nf][3];
            *(bf16x4*)(hs + row * 256 + (col8 ^ ((row & 15) << 4))) = o;
        }
        __syncthreads();

        // coalesced store of this pass's 128-hc stripe: 1024 x 16B tasks
#pragma unroll
        for (int it = 0; it < 2; ++it) {
            int ci = it * 512 + tid;         // 0..1023
            int row = ci >> 4, c = ci & 15;
            bf16x8 v = *(const bf16x8*)(hs + row * 256 + ((c * 16) ^ ((row & 15) << 4)));
            long node = nb + row;
            if (node < NNODES)
                *(bf16x8*)(UV + node * 512 + p * 128 + c * 8) = v;
        }
        __syncthreads();   // hs reused next pass
    }
}

// =================== phase 2: pred = W2.relu(u_i + v_j + b1) + b2 ===================
// 2 pairs per wave (lane halves), 16B/lane; measured-best simple form (r6: 74.3us).
__launch_bounds__(512)
__global__ void pair_pred(const bf16* __restrict__ UV, const int* __restrict__ junc,
                          const float* __restrict__ b1, const float* __restrict__ w2,
                          const float* __restrict__ b2, float* __restrict__ out) {
    int tid = threadIdx.x;
    int lane = tid & 63, half = lane >> 5, l31 = lane & 31;
    long gw = (long)blockIdx.x * 8 + (tid >> 6);   // 0..8191
    float b1c[8], w2c[8];
#pragma unroll
    for (int e = 0; e < 8; ++e) {
        int col = l31 * 8 + e;
        b1c[e] = b1[col];
        w2c[e] = w2[col];
    }
    float b2v = b2[0];
    const long HALF = NPAIRS / 2;     // 250000
    for (long q = gw; q < HALF; q += 8192) {
        long p = 2 * q + half;
        int2 ij = ((const int2*)junc)[p];
        bf16x8 u = *(const bf16x8*)(UV + (long)ij.x * 512 + l31 * 8);
        bf16x8 v = *(const bf16x8*)(UV + (long)ij.y * 512 + 256 + l31 * 8);
        float s = 0.f;
#pragma unroll
        for (int e = 0; e < 8; ++e) {
            float h = (float)u[e] + (float)v[e] + b1c[e];
            s = fmaf(fmaxf(h, 0.f), w2c[e], s);
        }
        s += __shfl_xor(s, 1);
        s += __shfl_xor(s, 2);
        s += __shfl_xor(s, 4);
        s += __shfl_xor(s, 8);
        s += __shfl_xor(s, 16);
        if (l31 == 0) out[p] = s + b2v;
    }
}

// =================== fallback (small ws): fused, known-correct ===================
__global__ void pack_w1(const float* __restrict__ W1, bf16* __restrict__ w1f) {
    int t = blockIdx.x * 256 + threadIdx.x;
    int lane = t & 63;
    int kk = (t >> 6) & 7;
    int cg = t >> 9;
    int l15 = lane & 15, lg = lane >> 4;
    bf16x8 v;
#pragma unroll
    for (int j = 0; j < 8; ++j)
        v[j] = (bf16)W1[(long)(kk * 32 + lg * 8 + j) * D2 + cg * 16 + l15];
    *(bf16x8*)((char*)w1f + ((long)t << 4)) = v;
}

__launch_bounds__(512, 2)
__global__ void fused_fb(const float* __restrict__ x, const int* __restrict__ junc,
                         const bf16* __restrict__ w1f, const float* __restrict__ b1,
                         const float* __restrict__ w2p, const float* __restrict__ b2,
                         float* __restrict__ out) {
    __shared__ char  atile[128 * 512];
    __shared__ float outp[4][128];
    int tid  = threadIdx.x;
    int wave = tid >> 6, lane = tid & 63;
    int l15 = lane & 15, lg = lane >> 4;
    int wr = wave >> 2, wc = wave & 3;
    long base_p = (long)blockIdx.x * 128;

    float bb[4][4], ww[4][4];
#pragma unroll
    for (int m = 0; m < 4; ++m)
#pragma unroll
        for (int r = 0; r < 4; ++r) {
            int hc = wc * 64 + m * 16 + lg * 4 + r;
            bb[m][r] = b1[hc];
            ww[m][r] = w2p[hc];
        }
#pragma unroll
    for (int it = 0; it < 8; ++it) {
        int task  = it * 512 + tid;
        int nr = task >> 4, chunk = task & 15;
        int r = nr >> 1, side = nr & 1;
        long p = base_p + r;
        int idx = (p < NPAIRS) ? junc[p * 2 + side] : 0;
        const float4* src = (const float4*)(x + (long)idx * DIM + chunk * 8);
        float4 a = src[0], b = src[1];
        bf16x8 v;
        v[0]=(bf16)a.x; v[1]=(bf16)a.y; v[2]=(bf16)a.z; v[3]=(bf16)a.w;
        v[4]=(bf16)b.x; v[5]=(bf16)b.y; v[6]=(bf16)b.z; v[7]=(bf16)b.w;
        int bir = side * 256 + chunk * 16;
        *(bf16x8*)(atile + r * 512 + (bir ^ ((r & 31) << 4))) = v;
    }
    __syncthreads();

    f32x4 acc[4][4];
#pragma unroll
    for (int m = 0; m < 4; ++m)
#pragma unroll
        for (int n = 0; n < 4; ++n)
            acc[m][n] = (f32x4){0.f, 0.f, 0.f, 0.f};
#pragma unroll
    for (int kk = 0; kk < 8; ++kk) {
        bf16x8 xf[4];
        int kbyte = kk * 64 + lg * 16;
#pragma unroll
        for (int n = 0; n < 4; ++n) {
            int r = wr * 64 + n * 16 + l15;
            xf[n] = *(const bf16x8*)(atile + r * 512 + (kbyte ^ ((r & 31) << 4)));
        }
#pragma unroll
        for (int m = 0; m < 4; ++m) {
            bf16x8 wf = *(const bf16x8*)((const char*)w1f +
                            ((((wc * 4 + m) * 8 + kk) * 64 + lane) << 4));
#pragma unroll
            for (int n = 0; n < 4; ++n)
                acc[m][n] = __builtin_amdgcn_mfma_f32_16x16x32_bf16(wf, xf[n], acc[m][n], 0, 0, 0);
        }
    }
#pragma unroll
    for (int n = 0; n < 4; ++n) {
        float s = 0.f;
#pragma unroll
        for (int m = 0; m < 4; ++m)
#pragma unroll
            for (int r = 0; r < 4; ++r)
                s = fmaf(fmaxf(acc[m][n][r] + bb[m][r], 0.f), ww[m][r], s);
        s += __shfl_xor(s, 16);
        s += __shfl_xor(s, 32);
        if (lg == 0) outp[wc][wr * 64 + n * 16 + l15] = s;
    }
    __syncthreads();
    if (tid < 128) {
        long p = base_p + tid;
        if (p < NPAIRS)
            out[p] = b2[0] + outp[0][tid] + outp[1][tid] + outp[2][tid] + outp[3][tid];
    }
}

extern "C" void kernel_launch(void* const* d_in, const int* in_sizes, int n_in,
                              void* d_out, int out_size, void* d_ws, size_t ws_size,
                              hipStream_t stream) {
    const float* x    = (const float*)d_in[0];
    const int*   junc = (const int*)  d_in[1];
    const float* W1   = (const float*)d_in[2];
    const float* b1   = (const float*)d_in[3];
    const float* W2   = (const float*)d_in[4];
    const float* b2   = (const float*)d_in[5];
    float* out = (float*)d_out;

    const size_t UV_B  = (size_t)NNODES * 512 * 2;    // 102,400,000
    const size_t NEED  = UV_B + 131072;

    if (ws_size >= NEED) {
        bf16* UV  = (bf16*)d_ws;
        bf16* w1p = (bf16*)((char*)d_ws + UV_B);
        hipLaunchKernelGGL(pack_w1p, dim3(32), dim3(256), 0, stream, W1, w1p);
        hipLaunchKernelGGL(gemm_uv, dim3((NNODES + 63) / 64), dim3(512), 0, stream,
                           x, w1p, UV);
        hipLaunchKernelGGL(pair_pred, dim3(1024), dim3(512), 0, stream,
                           UV, junc, b1, W2, b2, out);
    } else {
        bf16* w1f = (bf16*)d_ws;
        hipLaunchKernelGGL(pack_w1, dim3(32), dim3(256), 0, stream, W1, w1f);
        hipLaunchKernelGGL(fused_fb, dim3((NPAIRS + 127) / 128), dim3(512), 0, stream,
                           x, junc, w1f, b1, W2, b2, out);
    }
}